// Round 9
// baseline (223.993 us; speedup 1.0000x reference)
//
#include <hip/hip_runtime.h>

typedef short short8 __attribute__((ext_vector_type(8)));
typedef short short4v __attribute__((ext_vector_type(4)));
typedef float f4 __attribute__((ext_vector_type(4)));

#define NB 4
#define NHW 128
#define NPX (NHW*NHW)
#define NWIN 31
#define NL (NWIN*NWIN)
// 64-wide row, 8-col-block XOR swizzle (conflict-free b128 row reads)
#define SWV(r,c) (((r)<<6) + (((((c)>>3) ^ ((r)&7))<<3) | ((c)&7)))
#define MFMA(a,b,c) __builtin_amdgcn_mfma_f32_16x16x32_bf16(a,b,c,0,0,0)

__device__ __forceinline__ short f2bf(float f) {
    unsigned u = __float_as_uint(f);
    u += 0x7fffu + ((u >> 16) & 1u);   // RNE; inputs never NaN/inf
    return (short)(u >> 16);
}
__device__ __forceinline__ short f2bft(float f) {   // truncate (P only; self-normalized)
    return (short)(__float_as_uint(f) >> 16);
}
__device__ __forceinline__ float bf2f(short v) {
    return __uint_as_float(((unsigned)(unsigned short)v) << 16);
}

// ---------------- SE: global average pool per (b,c) ----------------
__global__ void k_pool(const float* __restrict__ high, float* __restrict__ pooled) {
    int bc = blockIdx.x;
    const float* src = high + (size_t)bc * NPX;
    float s = 0.f;
    for (int i = threadIdx.x; i < NPX; i += 256) s += src[i];
    for (int off = 32; off > 0; off >>= 1) s += __shfl_down(s, off);
    __shared__ float red[4];
    int lane = threadIdx.x & 63, wv = threadIdx.x >> 6;
    if (lane == 0) red[wv] = s;
    __syncthreads();
    if (threadIdx.x == 0)
        pooled[bc] = (red[0] + red[1] + red[2] + red[3]) * (1.f / NPX);
}

// ---------------- SE gate + Wp fp32->bf16 conversion ----------------
__global__ void k_gate(const float* __restrict__ pooled,
                       const float* __restrict__ w10, const float* __restrict__ w20,
                       const float* __restrict__ w11, const float* __restrict__ w21,
                       const float* __restrict__ w12, const float* __restrict__ w22,
                       const float* __restrict__ wpl, const float* __restrict__ wph,
                       float* __restrict__ sgate, short* __restrict__ wbf) {
    __shared__ float pl[256];
    int t = threadIdx.x;
    pl[t] = pooled[t];
    // convert both projection matrices to bf16 (8192 elems)
    #pragma unroll
    for (int i = 0; i < 32; ++i) {
        int idx = t + i*256;
        const float* src = (idx < 4096) ? wpl : wph;
        wbf[idx] = f2bf(src[idx & 4095]);
    }
    __syncthreads();
    int b = t >> 6, c = t & 63;
    const float* w1; const float* w2; int o0, gc;
    if (c < 22)      { w1 = w10; w2 = w20; o0 = 0;  gc = 22; }
    else if (c < 43) { w1 = w11; w2 = w21; o0 = 22; gc = 21; }
    else             { w1 = w12; w2 = w22; o0 = 43; gc = 21; }
    float a = 0.f;
    for (int k = 0; k < gc; ++k) a += pl[b*64 + o0 + k] * w1[k];
    a = fmaxf(a, 0.f);
    float z = a * w2[c - o0];
    sgate[t] = 1.f / (1.f + __expf(-z));
}

// windows covering coordinate x (ws=8, stride 4): [lo,hi]
__device__ __forceinline__ void wrange(int x, int& lo, int& hi) {
    lo = (x >= 7) ? ((x - 4) >> 2) : 0;
    hi = x >> 2; if (hi > 30) hi = 30;
}

// ---------------- projection body (shared) ----------------
// Q is pre-scaled by 0.25 (attention scale folded in).
template<int EMIT>
__device__ __forceinline__ void proj_body(
    const float* __restrict__ src, const float* __restrict__ gate,
    const float* __restrict__ Wq, const float* __restrict__ Wk, const float* __restrict__ Wv,
    short* __restrict__ Qp, short* __restrict__ Kp, short* __restrict__ Vp,
    short* T, int b, int row, int t) {
    const float* sp = src + (size_t)b*64*NPX + row*NHW;
    #pragma unroll
    for (int i = 0; i < 8; ++i) {
        int f = t + i*256;
        int c = f & 63, px = (f >> 6) << 2;
        float4 v = *(const float4*)(sp + (size_t)c*NPX + px);
        float g = gate ? gate[b*64 + c] : 1.f;
        T[SWV(px + 0, c)] = f2bf(v.x * g);
        T[SWV(px + 1, c)] = f2bf(v.y * g);
        T[SWV(px + 2, c)] = f2bf(v.z * g);
        T[SWV(px + 3, c)] = f2bf(v.w * g);
    }
    __syncthreads();
    int w = t >> 6, ln = t & 63, l16 = ln & 15, quad = ln >> 4;
    int orow = 16*w + l16;
    short8 wq[2], wk[2], wv[2];
    #pragma unroll
    for (int kf = 0; kf < 2; ++kf) {
        if (EMIT & 1) {
            const float* p = Wq + orow*64 + kf*32 + quad*8;
            #pragma unroll
            for (int j = 0; j < 8; ++j) wq[kf][j] = f2bf(p[j]);
        }
        if (EMIT & 2) {
            const float* p = Wk + orow*64 + kf*32 + quad*8;
            #pragma unroll
            for (int j = 0; j < 8; ++j) wk[kf][j] = f2bf(p[j]);
        }
        if (EMIT & 4) {
            const float* p = Wv + orow*64 + kf*32 + quad*8;
            #pragma unroll
            for (int j = 0; j < 8; ++j) wv[kf][j] = f2bf(p[j]);
        }
    }
    #pragma unroll
    for (int nt = 0; nt < 8; ++nt) {
        int px = nt*16 + l16;
        short8 xb0 = *(const short8*)(T + SWV(px, quad*8));
        short8 xb1 = *(const short8*)(T + SWV(px, 32 + quad*8));
        size_t clbase = ((size_t)b*NPX + row*NHW + px)*64 + 16*w + quad*4;
        if (EMIT & 1) {
            f4 acc = {0.f,0.f,0.f,0.f};
            acc = MFMA(wq[0], xb0, acc); acc = MFMA(wq[1], xb1, acc);
            short4v sv;
            #pragma unroll
            for (int r = 0; r < 4; ++r) sv[r] = f2bf(acc[r] * 0.25f);
            *(short4v*)(Qp + clbase) = sv;
        }
        if (EMIT & 2) {
            f4 acc = {0.f,0.f,0.f,0.f};
            acc = MFMA(wk[0], xb0, acc); acc = MFMA(wk[1], xb1, acc);
            short4v sv;
            #pragma unroll
            for (int r = 0; r < 4; ++r) sv[r] = f2bf(acc[r]);
            *(short4v*)(Kp + clbase) = sv;
        }
        if (EMIT & 4) {
            f4 acc = {0.f,0.f,0.f,0.f};
            acc = MFMA(wv[0], xb0, acc); acc = MFMA(wv[1], xb1, acc);
            #pragma unroll
            for (int r = 0; r < 4; ++r)
                Vp[((size_t)(b*64 + 16*w + quad*4 + r))*NPX + row*NHW + px] = f2bf(acc[r]);
        }
    }
}

// single-source projection (fallback paths)
template<int EMIT>
__global__ __launch_bounds__(256, 6) void k_proj(
    const float* __restrict__ src, const float* __restrict__ gate,
    const float* __restrict__ Wq, const float* __restrict__ Wk, const float* __restrict__ Wv,
    short* __restrict__ Qp, short* __restrict__ Kp, short* __restrict__ Vp) {
    __shared__ __align__(16) short T[8192];
    proj_body<EMIT>(src, gate, Wq, Wk, Wv, Qp, Kp, Vp, T,
                    blockIdx.x >> 7, blockIdx.x & 127, threadIdx.x);
}

// fused both-source projection: bidx&7 = (srcsel<<2)|b region -> XCD-local
__global__ __launch_bounds__(256, 6) void k_proj2(
    const float* __restrict__ s0, const float* __restrict__ s1, const float* __restrict__ gate,
    const float* __restrict__ Wq0, const float* __restrict__ Wk0, const float* __restrict__ Wv0,
    const float* __restrict__ Wq1, const float* __restrict__ Wk1, const float* __restrict__ Wv1,
    short* __restrict__ Q0, short* __restrict__ K0, short* __restrict__ V0,
    short* __restrict__ Q1, short* __restrict__ K1, short* __restrict__ V1) {
    __shared__ __align__(16) short T[8192];
    int region = blockIdx.x & 7;
    int ss = region >> 2, b = region & 3, row = blockIdx.x >> 3;
    if (ss == 0)
        proj_body<7>(s0, nullptr, Wq0, Wk0, Wv0, Q0, K0, V0, T, b, row, threadIdx.x);
    else
        proj_body<7>(s1, gate, Wq1, Wk1, Wv1, Q1, K1, V1, T, b, row, threadIdx.x);
}

// ---------------- windowed cross attention (S, softmax, PV only) ----------------
// SWZ=1 (fused, grid=8*NL): blockIdx%8 -> (pass,b): each XCD owns one plane.
// Softmax denominator via MFMA ones-trick: O = (V*P_hat) * rcp(sum(P_hat)).
// scr: [pass][4 parity][nb][px][64] bf16; same-parity windows tile the plane.
template<int SWZ>
__global__ __launch_bounds__(256, 6) void k_attn(
    const short* __restrict__ Q0, const short* __restrict__ K0, const short* __restrict__ V0,
    const short* __restrict__ Q1, const short* __restrict__ K1, const short* __restrict__ V1,
    short* __restrict__ scr, size_t scr_stride, int nb) {
    __shared__ __align__(16) short Pb[4][1024];   // per-wave P [16 n][64 m], swizzled
    int bidx = blockIdx.x;
    int pass, b, l;
    if (SWZ) {
        int region = bidx & 7;
        pass = region >> 2; b = region & 3; l = bidx >> 3;
    } else {
        int per = nb * NL;
        pass = bidx / per; int rem2 = bidx - pass*per;
        b = rem2 / NL; l = rem2 - b*NL;
    }
    const short* Qp = pass ? Q1 : Q0;
    const short* Kp = pass ? K1 : K0;
    const short* Vp = pass ? V1 : V0;
    short* scrp = scr + (size_t)pass * scr_stride;
    int wr = l / NWIN, wc = l - (l/NWIN)*NWIN;
    int row0 = wr*4, col0 = wc*4;
    int parity = (wr & 1)*2 + (wc & 1);
    int t = threadIdx.x, w = t >> 6, ln = t & 63, l16 = ln & 15, quad = ln >> 4;
    int h = w;
    short* PT = Pb[w];
    short8 z = {0,0,0,0,0,0,0,0};
    const short one = (short)0x3F80;   // bf16 1.0
    short8 ones = {one,one,one,one,one,one,one,one};

    // K B-frags: B[k=d][col=m], m = mt*16+l16, d = quad*8+j (quad<2)
    short8 kb[4];
    #pragma unroll
    for (int mt = 0; mt < 4; ++mt) {
        int m = mt*16 + l16;
        int px = (row0 + (m >> 3))*NHW + col0 + (m & 7);
        kb[mt] = (quad < 2) ? *(const short8*)(Kp + ((size_t)b*NPX + px)*64 + h*16 + quad*8) : z;
    }
    // V A-frags: A[row=d=l16][k=m]; planar V: row rr, 8 consecutive cols
    short8 va0, va1;
    {
        const short* vb = Vp + ((size_t)(b*64 + h*16 + l16))*NPX;
        const short* p0 = vb + (row0 + quad)*NHW + col0;
        const short* p1 = vb + (row0 + 4 + quad)*NHW + col0;
        short4v a = *(const short4v*)p0, bq = *(const short4v*)(p0 + 4);
        short4v c = *(const short4v*)p1, d = *(const short4v*)(p1 + 4);
        #pragma unroll
        for (int j = 0; j < 4; ++j) { va0[j] = a[j]; va0[4+j] = bq[j]; va1[j] = c[j]; va1[4+j] = d[j]; }
    }

    #pragma unroll
    for (int ntl = 0; ntl < 4; ++ntl) {
        int n = ntl*16 + l16;
        int px = (row0 + (n >> 3))*NHW + col0 + (n & 7);
        short8 qa = (quad < 2) ? *(const short8*)(Qp + ((size_t)b*NPX + px)*64 + h*16 + quad*8) : z;
        f4 s[4];
        #pragma unroll
        for (int mt = 0; mt < 4; ++mt) {
            f4 acc = {0.f,0.f,0.f,0.f};
            s[mt] = MFMA(qa, kb[mt], acc);
        }
        // unnormalized exp (Q pre-scaled by 0.25; clamp for safety)
        #pragma unroll
        for (int mt = 0; mt < 4; ++mt)
            #pragma unroll
            for (int r = 0; r < 4; ++r)
                PT[SWV(quad*4 + r, mt*16 + l16)] = f2bft(__expf(fminf(s[mt][r], 30.f)));
        // O[d][n] = V_h P^T; denom[n] = ones * P^T (same B-frags, col-aligned)
        short8 pb0 = *(const short8*)(PT + SWV(l16, quad*8));
        short8 pb1 = *(const short8*)(PT + SWV(l16, 32 + quad*8));
        f4 o = {0.f,0.f,0.f,0.f};
        o = MFMA(va0, pb0, o);
        o = MFMA(va1, pb1, o);
        f4 dn = {0.f,0.f,0.f,0.f};
        dn = MFMA(ones, pb0, dn);
        dn = MFMA(ones, pb1, dn);
        float inv = __builtin_amdgcn_rcpf(dn[0]);
        short4v sv;
        #pragma unroll
        for (int r = 0; r < 4; ++r) sv[r] = f2bf(o[r] * inv);
        *(short4v*)(scrp + (((size_t)(parity*nb + b))*NPX + px)*64 + h*16 + quad*4) = sv;
    }
}

// ---------------- fold + mask + 1x1 proj + residual, pure-MFMA, no LDS ----------------
// mask division is per-pixel (per GEMM column) so it commutes with Wp; parity
// fold is accumulation -> acc += Wp_frag x O_par_frag over 4 parities.
// Each wave: all 64 out-ch x 16 px. scr read exactly once. wpb = bf16 Wp pair.
template<int SWZ>
__global__ __launch_bounds__(256, 4) void k_gather(
    const short* __restrict__ scr, size_t scr_stride,
    const float* __restrict__ r0, const float* __restrict__ r1,
    const short* __restrict__ wpb,
    float* __restrict__ o0, float* __restrict__ o1, int nb) {
    int bidx = blockIdx.x;
    int pass, b, hh, half;
    if (SWZ) {
        int region = bidx & 7;
        pass = region >> 2; b = region & 3;
        int rem2 = bidx >> 3; hh = rem2 >> 1; half = rem2 & 1;
    } else {
        pass = 0;
        b = bidx / (NHW*2); int rem2 = bidx - b*(NHW*2);
        hh = rem2 >> 1; half = rem2 & 1;
    }
    const short* scrp = scr + (size_t)pass * scr_stride;
    const float* resid = pass ? r1 : r0;
    const short* wproj = wpb + (SWZ ? pass*4096 : 0);
    float* outp = pass ? o1 : o0;
    int t = threadIdx.x, w = t >> 6, ln = t & 63, l16 = ln & 15, quad = ln >> 4;
    int px = half*64 + w*16 + l16;          // this lane's pixel column
    int rlo, rhi, clo, chi;
    wrange(hh, rlo, rhi); wrange(px, clo, chi);
    bool okr0 = (rhi > rlo) || ((rlo & 1) == 0);
    bool okr1 = (rhi > rlo) || ((rlo & 1) == 1);
    bool okc0 = (chi > clo) || ((clo & 1) == 0);
    bool okc1 = (chi > clo) || ((clo & 1) == 1);
    // A-frags: Wp rows ct*16+l16, k = kf*32+quad*8+j (bf16, pre-converted)
    short8 wa[4][2];
    #pragma unroll
    for (int ct = 0; ct < 4; ++ct)
        #pragma unroll
        for (int kf = 0; kf < 2; ++kf)
            wa[ct][kf] = *(const short8*)(wproj + (ct*16 + l16)*64 + kf*32 + quad*8);
    f4 acc[4];
    #pragma unroll
    for (int ct = 0; ct < 4; ++ct) acc[ct] = (f4){0.f,0.f,0.f,0.f};
    short8 z = {0,0,0,0,0,0,0,0};
    #pragma unroll
    for (int par = 0; par < 4; ++par) {
        bool valid = ((par >> 1) ? okr1 : okr0) && ((par & 1) ? okc1 : okc0);
        const short* sp2 = scrp + (((size_t)(par*nb + b))*NPX + hh*NHW + px)*64;
        short8 b0 = *(const short8*)(sp2 + quad*8);
        short8 b1 = *(const short8*)(sp2 + 32 + quad*8);
        if (!valid) { b0 = z; b1 = z; }
        #pragma unroll
        for (int ct = 0; ct < 4; ++ct) {
            acc[ct] = MFMA(wa[ct][0], b0, acc[ct]);
            acc[ct] = MFMA(wa[ct][1], b1, acc[ct]);
        }
    }
    float inv = 1.f / ((float)(rhi - rlo + 1) * (float)(chi - clo + 1));
    #pragma unroll
    for (int ct = 0; ct < 4; ++ct)
        #pragma unroll
        for (int r = 0; r < 4; ++r) {
            size_t gi = (((size_t)(b*64 + ct*16 + quad*4 + r))*NHW + hh)*NHW + px;
            outp[gi] = resid[gi] + acc[ct][r] * inv;
        }
}

extern "C" void kernel_launch(void* const* d_in, const int* in_sizes, int n_in,
                              void* d_out, int out_size, void* d_ws, size_t ws_size,
                              hipStream_t stream) {
    const float* low  = (const float*)d_in[0];
    const float* high = (const float*)d_in[1];
    const float* w_ql = (const float*)d_in[2];
    const float* w_kh = (const float*)d_in[3];
    const float* w_vh = (const float*)d_in[4];
    const float* w_qh = (const float*)d_in[5];
    const float* w_kl = (const float*)d_in[6];
    const float* w_vl = (const float*)d_in[7];
    const float* w_pl = (const float*)d_in[8];
    const float* w_ph = (const float*)d_in[9];
    float* out = (float*)d_out;
    float* pooled = (float*)d_ws;
    float* sgate  = pooled + 256;
    short* wbf = (short*)((char*)d_ws + 2048);          // 2 x 4096 bf16 Wp
    short* base = wbf + 8192;
    const size_t PL = (size_t)NB * NPX * 64;            // elems per bf16 plane (8.39 MB)
    const size_t plane_f = (size_t)NB * 64 * NPX;       // fp32 out plane elems
    const size_t SCR = 4 * PL;                          // scr elems per pass (33.5 MB)
    const size_t HDR = 2048 + 8192*sizeof(short);
    size_t need_fused  = HDR + (6*PL + 2*SCR) * sizeof(short);
    size_t need_serial = HDR + (6*PL + SCR) * sizeof(short);
    size_t scr_elems_per_b = 4 * (size_t)NPX * 64;

    k_pool<<<dim3(NB*64), dim3(256), 0, stream>>>(high, pooled);
    k_gate<<<dim3(1), dim3(256), 0, stream>>>(pooled,
        (const float*)d_in[10], (const float*)d_in[11],
        (const float*)d_in[12], (const float*)d_in[13],
        (const float*)d_in[14], (const float*)d_in[15],
        w_pl, w_ph, sgate, wbf);

    if (ws_size >= need_serial) {
        short* QL = base;        short* KL = base + PL;   short* VL = base + 2*PL;
        short* QH = base + 3*PL; short* KH = base + 4*PL; short* VH = base + 5*PL;
        short* scr = base + 6*PL;
        k_proj2<<<dim3(8*NHW), dim3(256), 0, stream>>>(low, high, sgate,
            w_ql, w_kl, w_vl, w_qh, w_kh, w_vh,
            QL, KL, VL, QH, KH, VH);
        if (ws_size >= need_fused) {
            k_attn<1><<<dim3(8*NL), dim3(256), 0, stream>>>(QL, KH, VH, QH, KL, VL, scr, SCR, NB);
            k_gather<1><<<dim3(8*NHW*2), dim3(256), 0, stream>>>(scr, SCR, low, high,
                wbf, out, out + plane_f, NB);
        } else {
            k_attn<0><<<dim3(NB*NL), dim3(256), 0, stream>>>(QL, KH, VH, nullptr, nullptr, nullptr, scr, 0, NB);
            k_gather<0><<<dim3(NB*NHW*2), dim3(256), 0, stream>>>(scr, 0, low, nullptr,
                wbf, out, nullptr, NB);
            k_attn<0><<<dim3(NB*NL), dim3(256), 0, stream>>>(QH, KL, VL, nullptr, nullptr, nullptr, scr, 0, NB);
            k_gather<0><<<dim3(NB*NHW*2), dim3(256), 0, stream>>>(scr, 0, high, nullptr,
                wbf + 4096, out + plane_f, nullptr, NB);
        }
    } else {
        // trio mode: 3 plane slots + batch-chunked scr
        short* P0 = base; short* P1 = base + PL; short* P2 = base + 2*PL;
        short* scr = base + 3*PL;
        int nbc = 0;
        for (int n = NB; n >= 1; n >>= 1)
            if (ws_size >= HDR + (3*PL + n*scr_elems_per_b)*sizeof(short)) { nbc = n; break; }
        if (nbc == 0) nbc = 1;
        for (int pass = 0; pass < 2; ++pass) {
            const float* qsrc = pass ? high : low;
            const float* ksrc = pass ? low  : high;
            const float* qg   = pass ? sgate : nullptr;
            const float* kg   = pass ? nullptr : sgate;
            const float* Wq   = pass ? w_qh : w_ql;
            const float* Wk   = pass ? w_kl : w_kh;
            const float* Wv   = pass ? w_vl : w_vh;
            const short* Wpb  = wbf + pass*4096;
            const float* resid = pass ? high : low;
            float* op = out + (size_t)pass * plane_f;
            k_proj<1><<<dim3(NB*NHW), dim3(256), 0, stream>>>(qsrc, qg, Wq, nullptr, nullptr, P0, nullptr, nullptr);
            k_proj<6><<<dim3(NB*NHW), dim3(256), 0, stream>>>(ksrc, kg, nullptr, Wk, Wv, nullptr, P1, P2);
            for (int b0 = 0; b0 < NB; b0 += nbc) {
                int nb = (NB - b0) < nbc ? (NB - b0) : nbc;
                size_t boff = (size_t)b0 * NPX * 64;
                k_attn<0><<<dim3(nb*NL), dim3(256), 0, stream>>>(P0 + boff, P1 + boff, P2 + boff,
                    nullptr, nullptr, nullptr, scr, 0, nb);
                k_gather<0><<<dim3(nb*NHW*2), dim3(256), 0, stream>>>(scr, 0, resid + boff, nullptr,
                    Wpb, op + boff, nullptr, nb);
            }
        }
    }
}

// Round 10
// 208.156 us; speedup vs baseline: 1.0761x; 1.0761x over previous
//
#include <hip/hip_runtime.h>

typedef short short8 __attribute__((ext_vector_type(8)));
typedef short short4v __attribute__((ext_vector_type(4)));
typedef float f4 __attribute__((ext_vector_type(4)));

#define NB 4
#define NHW 128
#define NPX (NHW*NHW)
#define NWIN 31
#define NL (NWIN*NWIN)
// 64-wide row, 8-col-block XOR swizzle (conflict-free b128 row reads)
#define SWV(r,c) (((r)<<6) + (((((c)>>3) ^ ((r)&7))<<3) | ((c)&7)))
#define MFMA(a,b,c) __builtin_amdgcn_mfma_f32_16x16x32_bf16(a,b,c,0,0,0)

__device__ __forceinline__ short f2bf(float f) {
    unsigned u = __float_as_uint(f);
    u += 0x7fffu + ((u >> 16) & 1u);   // RNE; inputs never NaN/inf
    return (short)(u >> 16);
}
__device__ __forceinline__ short f2bft(float f) {   // truncate (P only; self-normalized)
    return (short)(__float_as_uint(f) >> 16);
}
__device__ __forceinline__ float bf2f(short v) {
    return __uint_as_float(((unsigned)(unsigned short)v) << 16);
}

// ---------------- SE: global average pool per (b,c) ----------------
__global__ void k_pool(const float* __restrict__ high, float* __restrict__ pooled) {
    int bc = blockIdx.x;
    const float4* src = (const float4*)(high + (size_t)bc * NPX);
    float s = 0.f;
    for (int i = threadIdx.x; i < NPX/4; i += 256) {
        float4 v = src[i];
        s += (v.x + v.y) + (v.z + v.w);
    }
    for (int off = 32; off > 0; off >>= 1) s += __shfl_down(s, off);
    __shared__ float red[4];
    int lane = threadIdx.x & 63, wv = threadIdx.x >> 6;
    if (lane == 0) red[wv] = s;
    __syncthreads();
    if (threadIdx.x == 0)
        pooled[bc] = (red[0] + red[1] + red[2] + red[3]) * (1.f / NPX);
}

// ---------------- SE gate + Wp fp32->bf16 conversion ----------------
__global__ void k_gate(const float* __restrict__ pooled,
                       const float* __restrict__ w10, const float* __restrict__ w20,
                       const float* __restrict__ w11, const float* __restrict__ w21,
                       const float* __restrict__ w12, const float* __restrict__ w22,
                       const float* __restrict__ wpl, const float* __restrict__ wph,
                       float* __restrict__ sgate, short* __restrict__ wbf) {
    __shared__ float pl[256];
    int t = threadIdx.x;
    pl[t] = pooled[t];
    // convert both projection matrices to bf16 (8192 elems)
    #pragma unroll
    for (int i = 0; i < 32; ++i) {
        int idx = t + i*256;
        const float* src = (idx < 4096) ? wpl : wph;
        wbf[idx] = f2bf(src[idx & 4095]);
    }
    __syncthreads();
    int b = t >> 6, c = t & 63;
    const float* w1; const float* w2; int o0, gc;
    if (c < 22)      { w1 = w10; w2 = w20; o0 = 0;  gc = 22; }
    else if (c < 43) { w1 = w11; w2 = w21; o0 = 22; gc = 21; }
    else             { w1 = w12; w2 = w22; o0 = 43; gc = 21; }
    float a = 0.f;
    for (int k = 0; k < gc; ++k) a += pl[b*64 + o0 + k] * w1[k];
    a = fmaxf(a, 0.f);
    float z = a * w2[c - o0];
    sgate[t] = 1.f / (1.f + __expf(-z));
}

// windows covering coordinate x (ws=8, stride 4): [lo,hi]
__device__ __forceinline__ void wrange(int x, int& lo, int& hi) {
    lo = (x >= 7) ? ((x - 4) >> 2) : 0;
    hi = x >> 2; if (hi > 30) hi = 30;
}

// ---------------- projection body (shared) ----------------
// Q is pre-scaled by 0.25 (attention scale folded in).
// LDS staging: c-major coalesced b32 loads (gate factor wave-uniform),
// transpose store as b64 (4 channels contiguous in T[px][c]).
template<int EMIT>
__device__ __forceinline__ void proj_body(
    const float* __restrict__ src, const float* __restrict__ gate,
    const float* __restrict__ Wq, const float* __restrict__ Wk, const float* __restrict__ Wv,
    short* __restrict__ Qp, short* __restrict__ Kp, short* __restrict__ Vp,
    short* T, int b, int row, int t) {
    const float* sp = src + (size_t)b*64*NPX + row*NHW;
    #pragma unroll
    for (int i = 0; i < 8; ++i) {
        int f = t + i*256;                  // 0..2047
        int px = f & 127, c4 = (f >> 7) << 2;   // c4 wave-uniform
        short4v sv;
        #pragma unroll
        for (int j = 0; j < 4; ++j) {
            float v = sp[(size_t)(c4 + j)*NPX + px];
            if (gate) v *= gate[b*64 + c4 + j];
            sv[j] = f2bf(v);
        }
        *(short4v*)(T + SWV(px, c4)) = sv;
    }
    __syncthreads();
    int w = t >> 6, ln = t & 63, l16 = ln & 15, quad = ln >> 4;
    int orow = 16*w + l16;
    short8 wq[2], wk[2], wv[2];
    #pragma unroll
    for (int kf = 0; kf < 2; ++kf) {
        if (EMIT & 1) {
            const float* p = Wq + orow*64 + kf*32 + quad*8;
            #pragma unroll
            for (int j = 0; j < 8; ++j) wq[kf][j] = f2bf(p[j]);
        }
        if (EMIT & 2) {
            const float* p = Wk + orow*64 + kf*32 + quad*8;
            #pragma unroll
            for (int j = 0; j < 8; ++j) wk[kf][j] = f2bf(p[j]);
        }
        if (EMIT & 4) {
            const float* p = Wv + orow*64 + kf*32 + quad*8;
            #pragma unroll
            for (int j = 0; j < 8; ++j) wv[kf][j] = f2bf(p[j]);
        }
    }
    #pragma unroll
    for (int nt = 0; nt < 8; ++nt) {
        int px = nt*16 + l16;
        short8 xb0 = *(const short8*)(T + SWV(px, quad*8));
        short8 xb1 = *(const short8*)(T + SWV(px, 32 + quad*8));
        size_t clbase = ((size_t)b*NPX + row*NHW + px)*64 + 16*w + quad*4;
        if (EMIT & 1) {
            f4 acc = {0.f,0.f,0.f,0.f};
            acc = MFMA(wq[0], xb0, acc); acc = MFMA(wq[1], xb1, acc);
            short4v sv;
            #pragma unroll
            for (int r = 0; r < 4; ++r) sv[r] = f2bf(acc[r] * 0.25f);
            *(short4v*)(Qp + clbase) = sv;
        }
        if (EMIT & 2) {
            f4 acc = {0.f,0.f,0.f,0.f};
            acc = MFMA(wk[0], xb0, acc); acc = MFMA(wk[1], xb1, acc);
            short4v sv;
            #pragma unroll
            for (int r = 0; r < 4; ++r) sv[r] = f2bf(acc[r]);
            *(short4v*)(Kp + clbase) = sv;
        }
        if (EMIT & 4) {
            f4 acc = {0.f,0.f,0.f,0.f};
            acc = MFMA(wv[0], xb0, acc); acc = MFMA(wv[1], xb1, acc);
            #pragma unroll
            for (int r = 0; r < 4; ++r)
                Vp[((size_t)(b*64 + 16*w + quad*4 + r))*NPX + row*NHW + px] = f2bf(acc[r]);
        }
    }
}

// single-source projection (fallback paths)
template<int EMIT>
__global__ __launch_bounds__(256, 6) void k_proj(
    const float* __restrict__ src, const float* __restrict__ gate,
    const float* __restrict__ Wq, const float* __restrict__ Wk, const float* __restrict__ Wv,
    short* __restrict__ Qp, short* __restrict__ Kp, short* __restrict__ Vp) {
    __shared__ __align__(16) short T[8192];
    proj_body<EMIT>(src, gate, Wq, Wk, Wv, Qp, Kp, Vp, T,
                    blockIdx.x >> 7, blockIdx.x & 127, threadIdx.x);
}

// fused both-source projection: bidx&7 = (srcsel<<2)|b region -> XCD-local
__global__ __launch_bounds__(256, 6) void k_proj2(
    const float* __restrict__ s0, const float* __restrict__ s1, const float* __restrict__ gate,
    const float* __restrict__ Wq0, const float* __restrict__ Wk0, const float* __restrict__ Wv0,
    const float* __restrict__ Wq1, const float* __restrict__ Wk1, const float* __restrict__ Wv1,
    short* __restrict__ Q0, short* __restrict__ K0, short* __restrict__ V0,
    short* __restrict__ Q1, short* __restrict__ K1, short* __restrict__ V1) {
    __shared__ __align__(16) short T[8192];
    int region = blockIdx.x & 7;
    int ss = region >> 2, b = region & 3, row = blockIdx.x >> 3;
    if (ss == 0)
        proj_body<7>(s0, nullptr, Wq0, Wk0, Wv0, Q0, K0, V0, T, b, row, threadIdx.x);
    else
        proj_body<7>(s1, gate, Wq1, Wk1, Wv1, Q1, K1, V1, T, b, row, threadIdx.x);
}

// ---------------- windowed cross attention (S, softmax, PV only) ----------------
// SWZ=1 (fused, grid=8*NL): blockIdx%8 -> (pass,b): each XCD owns one plane.
// S computed TRANSPOSED (A=K, B=Q) so P_hat C-layout is row-contiguous per
// thread -> 4x ds_write_b64 instead of 16x ds_write_b16 per ntl.
// Softmax denominator via MFMA ones-trick: O = (V*P_hat) * rcp(sum(P_hat)).
// scr: [pass][4 parity][nb][px][64] bf16; same-parity windows tile the plane.
template<int SWZ>
__global__ __launch_bounds__(256, 6) void k_attn(
    const short* __restrict__ Q0, const short* __restrict__ K0, const short* __restrict__ V0,
    const short* __restrict__ Q1, const short* __restrict__ K1, const short* __restrict__ V1,
    short* __restrict__ scr, size_t scr_stride, int nb) {
    __shared__ __align__(16) short Pb[4][1024];   // per-wave P^T-view [16 n][64 m], swizzled
    int bidx = blockIdx.x;
    int pass, b, l;
    if (SWZ) {
        int region = bidx & 7;
        pass = region >> 2; b = region & 3; l = bidx >> 3;
    } else {
        int per = nb * NL;
        pass = bidx / per; int rem2 = bidx - pass*per;
        b = rem2 / NL; l = rem2 - b*NL;
    }
    const short* Qp = pass ? Q1 : Q0;
    const short* Kp = pass ? K1 : K0;
    const short* Vp = pass ? V1 : V0;
    short* scrp = scr + (size_t)pass * scr_stride;
    int wr = l / NWIN, wc = l - (l/NWIN)*NWIN;
    int row0 = wr*4, col0 = wc*4;
    int parity = (wr & 1)*2 + (wc & 1);
    int t = threadIdx.x, w = t >> 6, ln = t & 63, l16 = ln & 15, quad = ln >> 4;
    int h = w;
    short* PT = Pb[w];
    short8 z = {0,0,0,0,0,0,0,0};
    const short one = (short)0x3F80;   // bf16 1.0
    short8 ones = {one,one,one,one,one,one,one,one};

    // K frags (A/B layouts coincide): lane l16 = m pixel, k = d = quad*8+j (quad<2)
    short8 kb[4];
    #pragma unroll
    for (int mt = 0; mt < 4; ++mt) {
        int m = mt*16 + l16;
        int px = (row0 + (m >> 3))*NHW + col0 + (m & 7);
        kb[mt] = (quad < 2) ? *(const short8*)(Kp + ((size_t)b*NPX + px)*64 + h*16 + quad*8) : z;
    }
    // V A-frags: A[row=d=l16][k=m]; planar V: row rr, 8 consecutive cols
    short8 va0, va1;
    {
        const short* vb = Vp + ((size_t)(b*64 + h*16 + l16))*NPX;
        const short* p0 = vb + (row0 + quad)*NHW + col0;
        const short* p1 = vb + (row0 + 4 + quad)*NHW + col0;
        short4v a = *(const short4v*)p0, bq = *(const short4v*)(p0 + 4);
        short4v c = *(const short4v*)p1, d = *(const short4v*)(p1 + 4);
        #pragma unroll
        for (int j = 0; j < 4; ++j) { va0[j] = a[j]; va0[4+j] = bq[j]; va1[j] = c[j]; va1[4+j] = d[j]; }
    }

    #pragma unroll
    for (int ntl = 0; ntl < 4; ++ntl) {
        int n = ntl*16 + l16;
        int px = (row0 + (n >> 3))*NHW + col0 + (n & 7);
        short8 qa = (quad < 2) ? *(const short8*)(Qp + ((size_t)b*NPX + px)*64 + h*16 + quad*8) : z;
        // S^T tiles: D[i=m][j=n]; lane value r -> m = mt*16+quad*4+r, n = ntl*16+l16
        #pragma unroll
        for (int mt = 0; mt < 4; ++mt) {
            f4 zz = {0.f,0.f,0.f,0.f};
            f4 s = MFMA(kb[mt], qa, zz);
            short4v pv;
            #pragma unroll
            for (int r = 0; r < 4; ++r)
                pv[r] = f2bft(__expf(fminf(s[r], 30.f)));
            *(short4v*)(PT + SWV(l16, mt*16 + quad*4)) = pv;   // 4 contiguous cols
        }
        // O[d][n] = V_h P^T; denom[n] = ones * P^T (same B-frags, col-aligned)
        short8 pb0 = *(const short8*)(PT + SWV(l16, quad*8));
        short8 pb1 = *(const short8*)(PT + SWV(l16, 32 + quad*8));
        f4 o = {0.f,0.f,0.f,0.f};
        o = MFMA(va0, pb0, o);
        o = MFMA(va1, pb1, o);
        f4 dn = {0.f,0.f,0.f,0.f};
        dn = MFMA(ones, pb0, dn);
        dn = MFMA(ones, pb1, dn);
        float inv = __builtin_amdgcn_rcpf(dn[0]);
        short4v sv;
        #pragma unroll
        for (int r = 0; r < 4; ++r) sv[r] = f2bf(o[r] * inv);
        *(short4v*)(scrp + (((size_t)(parity*nb + b))*NPX + px)*64 + h*16 + quad*4) = sv;
    }
}

// ---------------- fold + mask + 1x1 proj + residual, pure-MFMA, no LDS ----------------
// mask division is per-pixel (per GEMM column) so it commutes with Wp; parity
// fold is accumulation -> acc += Wp_frag x O_par_frag over 4 parities.
// Each wave: all 64 out-ch x 16 px. scr read exactly once. wpb = bf16 Wp pair.
template<int SWZ>
__global__ __launch_bounds__(256, 6) void k_gather(
    const short* __restrict__ scr, size_t scr_stride,
    const float* __restrict__ r0, const float* __restrict__ r1,
    const short* __restrict__ wpb,
    float* __restrict__ o0, float* __restrict__ o1, int nb) {
    int bidx = blockIdx.x;
    int pass, b, hh, half;
    if (SWZ) {
        int region = bidx & 7;
        pass = region >> 2; b = region & 3;
        int rem2 = bidx >> 3; hh = rem2 >> 1; half = rem2 & 1;
    } else {
        pass = 0;
        b = bidx / (NHW*2); int rem2 = bidx - b*(NHW*2);
        hh = rem2 >> 1; half = rem2 & 1;
    }
    const short* scrp = scr + (size_t)pass * scr_stride;
    const float* resid = pass ? r1 : r0;
    const short* wproj = wpb + (SWZ ? pass*4096 : 0);
    float* outp = pass ? o1 : o0;
    int t = threadIdx.x, w = t >> 6, ln = t & 63, l16 = ln & 15, quad = ln >> 4;
    int px = half*64 + w*16 + l16;          // this lane's pixel column
    int rlo, rhi, clo, chi;
    wrange(hh, rlo, rhi); wrange(px, clo, chi);
    bool okr0 = (rhi > rlo) || ((rlo & 1) == 0);
    bool okr1 = (rhi > rlo) || ((rlo & 1) == 1);
    bool okc0 = (chi > clo) || ((clo & 1) == 0);
    bool okc1 = (chi > clo) || ((clo & 1) == 1);
    // A-frags: Wp rows ct*16+l16, k = kf*32+quad*8+j (bf16, pre-converted)
    short8 wa[4][2];
    #pragma unroll
    for (int ct = 0; ct < 4; ++ct)
        #pragma unroll
        for (int kf = 0; kf < 2; ++kf)
            wa[ct][kf] = *(const short8*)(wproj + (ct*16 + l16)*64 + kf*32 + quad*8);
    f4 acc[4];
    #pragma unroll
    for (int ct = 0; ct < 4; ++ct) acc[ct] = (f4){0.f,0.f,0.f,0.f};
    short8 z = {0,0,0,0,0,0,0,0};
    #pragma unroll
    for (int par = 0; par < 4; ++par) {
        bool valid = ((par >> 1) ? okr1 : okr0) && ((par & 1) ? okc1 : okc0);
        const short* sp2 = scrp + (((size_t)(par*nb + b))*NPX + hh*NHW + px)*64;
        short8 b0 = *(const short8*)(sp2 + quad*8);
        short8 b1 = *(const short8*)(sp2 + 32 + quad*8);
        if (!valid) { b0 = z; b1 = z; }
        #pragma unroll
        for (int ct = 0; ct < 4; ++ct) {
            acc[ct] = MFMA(wa[ct][0], b0, acc[ct]);
            acc[ct] = MFMA(wa[ct][1], b1, acc[ct]);
        }
    }
    float inv = 1.f / ((float)(rhi - rlo + 1) * (float)(chi - clo + 1));
    #pragma unroll
    for (int ct = 0; ct < 4; ++ct)
        #pragma unroll
        for (int r = 0; r < 4; ++r) {
            size_t gi = (((size_t)(b*64 + ct*16 + quad*4 + r))*NHW + hh)*NHW + px;
            outp[gi] = resid[gi] + acc[ct][r] * inv;
        }
}

extern "C" void kernel_launch(void* const* d_in, const int* in_sizes, int n_in,
                              void* d_out, int out_size, void* d_ws, size_t ws_size,
                              hipStream_t stream) {
    const float* low  = (const float*)d_in[0];
    const float* high = (const float*)d_in[1];
    const float* w_ql = (const float*)d_in[2];
    const float* w_kh = (const float*)d_in[3];
    const float* w_vh = (const float*)d_in[4];
    const float* w_qh = (const float*)d_in[5];
    const float* w_kl = (const float*)d_in[6];
    const float* w_vl = (const float*)d_in[7];
    const float* w_pl = (const float*)d_in[8];
    const float* w_ph = (const float*)d_in[9];
    float* out = (float*)d_out;
    float* pooled = (float*)d_ws;
    float* sgate  = pooled + 256;
    short* wbf = (short*)((char*)d_ws + 2048);          // 2 x 4096 bf16 Wp
    short* base = wbf + 8192;
    const size_t PL = (size_t)NB * NPX * 64;            // elems per bf16 plane (8.39 MB)
    const size_t plane_f = (size_t)NB * 64 * NPX;       // fp32 out plane elems
    const size_t SCR = 4 * PL;                          // scr elems per pass (33.5 MB)
    const size_t HDR = 2048 + 8192*sizeof(short);
    size_t need_fused  = HDR + (6*PL + 2*SCR) * sizeof(short);
    size_t need_serial = HDR + (6*PL + SCR) * sizeof(short);
    size_t scr_elems_per_b = 4 * (size_t)NPX * 64;

    k_pool<<<dim3(NB*64), dim3(256), 0, stream>>>(high, pooled);
    k_gate<<<dim3(1), dim3(256), 0, stream>>>(pooled,
        (const float*)d_in[10], (const float*)d_in[11],
        (const float*)d_in[12], (const float*)d_in[13],
        (const float*)d_in[14], (const float*)d_in[15],
        w_pl, w_ph, sgate, wbf);

    if (ws_size >= need_serial) {
        short* QL = base;        short* KL = base + PL;   short* VL = base + 2*PL;
        short* QH = base + 3*PL; short* KH = base + 4*PL; short* VH = base + 5*PL;
        short* scr = base + 6*PL;
        k_proj2<<<dim3(8*NHW), dim3(256), 0, stream>>>(low, high, sgate,
            w_ql, w_kl, w_vl, w_qh, w_kh, w_vh,
            QL, KL, VL, QH, KH, VH);
        if (ws_size >= need_fused) {
            k_attn<1><<<dim3(8*NL), dim3(256), 0, stream>>>(QL, KH, VH, QH, KL, VL, scr, SCR, NB);
            k_gather<1><<<dim3(8*NHW*2), dim3(256), 0, stream>>>(scr, SCR, low, high,
                wbf, out, out + plane_f, NB);
        } else {
            k_attn<0><<<dim3(NB*NL), dim3(256), 0, stream>>>(QL, KH, VH, nullptr, nullptr, nullptr, scr, 0, NB);
            k_gather<0><<<dim3(NB*NHW*2), dim3(256), 0, stream>>>(scr, 0, low, nullptr,
                wbf, out, nullptr, NB);
            k_attn<0><<<dim3(NB*NL), dim3(256), 0, stream>>>(QH, KL, VL, nullptr, nullptr, nullptr, scr, 0, NB);
            k_gather<0><<<dim3(NB*NHW*2), dim3(256), 0, stream>>>(scr, 0, high, nullptr,
                wbf + 4096, out + plane_f, nullptr, NB);
        }
    } else {
        // trio mode: 3 plane slots + batch-chunked scr
        short* P0 = base; short* P1 = base + PL; short* P2 = base + 2*PL;
        short* scr = base + 3*PL;
        int nbc = 0;
        for (int n = NB; n >= 1; n >>= 1)
            if (ws_size >= HDR + (3*PL + n*scr_elems_per_b)*sizeof(short)) { nbc = n; break; }
        if (nbc == 0) nbc = 1;
        for (int pass = 0; pass < 2; ++pass) {
            const float* qsrc = pass ? high : low;
            const float* ksrc = pass ? low  : high;
            const float* qg   = pass ? sgate : nullptr;
            const float* kg   = pass ? nullptr : sgate;
            const float* Wq   = pass ? w_qh : w_ql;
            const float* Wk   = pass ? w_kl : w_kh;
            const float* Wv   = pass ? w_vl : w_vh;
            const short* Wpb  = wbf + pass*4096;
            const float* resid = pass ? high : low;
            float* op = out + (size_t)pass * plane_f;
            k_proj<1><<<dim3(NB*NHW), dim3(256), 0, stream>>>(qsrc, qg, Wq, nullptr, nullptr, P0, nullptr, nullptr);
            k_proj<6><<<dim3(NB*NHW), dim3(256), 0, stream>>>(ksrc, kg, nullptr, Wk, Wv, nullptr, P1, P2);
            for (int b0 = 0; b0 < NB; b0 += nbc) {
                int nb = (NB - b0) < nbc ? (NB - b0) : nbc;
                size_t boff = (size_t)b0 * NPX * 64;
                k_attn<0><<<dim3(nb*NL), dim3(256), 0, stream>>>(P0 + boff, P1 + boff, P2 + boff,
                    nullptr, nullptr, nullptr, scr, 0, nb);
                k_gather<0><<<dim3(nb*NHW*2), dim3(256), 0, stream>>>(scr, 0, resid + boff, nullptr,
                    Wpb, op + boff, nullptr, nb);
            }
        }
    }
}

// Round 11
// 207.970 us; speedup vs baseline: 1.0770x; 1.0009x over previous
//
#include <hip/hip_runtime.h>

typedef short short8 __attribute__((ext_vector_type(8)));
typedef short short4v __attribute__((ext_vector_type(4)));
typedef float f4 __attribute__((ext_vector_type(4)));

#define NB 4
#define NHW 128
#define NPX (NHW*NHW)
#define NWIN 31
#define NL (NWIN*NWIN)
// exp2 base change: Q prescale = 0.25 * log2(e); softmax identical exactly
#define QSCALE 0.3606737602f
// 64-wide row, 8-col-block XOR swizzle (conflict-free b128 row reads)
#define SWV(r,c) (((r)<<6) + (((((c)>>3) ^ ((r)&7))<<3) | ((c)&7)))
#define MFMA(a,b,c) __builtin_amdgcn_mfma_f32_16x16x32_bf16(a,b,c,0,0,0)

__device__ __forceinline__ short f2bf(float f) {
    unsigned u = __float_as_uint(f);
    u += 0x7fffu + ((u >> 16) & 1u);   // RNE; inputs never NaN/inf
    return (short)(u >> 16);
}
__device__ __forceinline__ short f2bft(float f) {   // truncate (P only; self-normalized)
    return (short)(__float_as_uint(f) >> 16);
}
__device__ __forceinline__ float bf2f(short v) {
    return __uint_as_float(((unsigned)(unsigned short)v) << 16);
}

// ---------------- SE: global average pool per (b,c) ----------------
__global__ void k_pool(const float* __restrict__ high, float* __restrict__ pooled) {
    int bc = blockIdx.x;
    const float4* src = (const float4*)(high + (size_t)bc * NPX);
    float s = 0.f;
    for (int i = threadIdx.x; i < NPX/4; i += 256) {
        float4 v = src[i];
        s += (v.x + v.y) + (v.z + v.w);
    }
    for (int off = 32; off > 0; off >>= 1) s += __shfl_down(s, off);
    __shared__ float red[4];
    int lane = threadIdx.x & 63, wv = threadIdx.x >> 6;
    if (lane == 0) red[wv] = s;
    __syncthreads();
    if (threadIdx.x == 0)
        pooled[bc] = (red[0] + red[1] + red[2] + red[3]) * (1.f / NPX);
}

// ---------------- SE gate + Wp fp32->bf16 conversion ----------------
__global__ void k_gate(const float* __restrict__ pooled,
                       const float* __restrict__ w10, const float* __restrict__ w20,
                       const float* __restrict__ w11, const float* __restrict__ w21,
                       const float* __restrict__ w12, const float* __restrict__ w22,
                       const float* __restrict__ wpl, const float* __restrict__ wph,
                       float* __restrict__ sgate, short* __restrict__ wbf) {
    __shared__ float pl[256];
    int t = threadIdx.x;
    pl[t] = pooled[t];
    // convert both projection matrices to bf16 (8192 elems)
    #pragma unroll
    for (int i = 0; i < 32; ++i) {
        int idx = t + i*256;
        const float* src = (idx < 4096) ? wpl : wph;
        wbf[idx] = f2bf(src[idx & 4095]);
    }
    __syncthreads();
    int b = t >> 6, c = t & 63;
    const float* w1; const float* w2; int o0, gc;
    if (c < 22)      { w1 = w10; w2 = w20; o0 = 0;  gc = 22; }
    else if (c < 43) { w1 = w11; w2 = w21; o0 = 22; gc = 21; }
    else             { w1 = w12; w2 = w22; o0 = 43; gc = 21; }
    float a = 0.f;
    for (int k = 0; k < gc; ++k) a += pl[b*64 + o0 + k] * w1[k];
    a = fmaxf(a, 0.f);
    float z = a * w2[c - o0];
    sgate[t] = 1.f / (1.f + __expf(-z));
}

// windows covering coordinate x (ws=8, stride 4): [lo,hi]
__device__ __forceinline__ void wrange(int x, int& lo, int& hi) {
    lo = (x >= 7) ? ((x - 4) >> 2) : 0;
    hi = x >> 2; if (hi > 30) hi = 30;
}

// ---------------- projection body (shared) ----------------
// Q pre-scaled by 0.25*log2(e) (exp2 softmax, exact). Q/K stored HEAD-MAJOR:
// [(b*4+h)][px][16] -> window fragment loads are 32 B-dense per pixel.
// V planar [b][64][px].
template<int EMIT>
__device__ __forceinline__ void proj_body(
    const float* __restrict__ src, const float* __restrict__ gate,
    const float* __restrict__ Wq, const float* __restrict__ Wk, const float* __restrict__ Wv,
    short* __restrict__ Qp, short* __restrict__ Kp, short* __restrict__ Vp,
    short* T, int b, int row, int t) {
    const float* sp = src + (size_t)b*64*NPX + row*NHW;
    #pragma unroll
    for (int i = 0; i < 8; ++i) {
        int f = t + i*256;                  // 0..2047
        int px = f & 127, c4 = (f >> 7) << 2;   // c4 wave-uniform
        short4v sv;
        #pragma unroll
        for (int j = 0; j < 4; ++j) {
            float v = sp[(size_t)(c4 + j)*NPX + px];
            if (gate) v *= gate[b*64 + c4 + j];
            sv[j] = f2bf(v);
        }
        *(short4v*)(T + SWV(px, c4)) = sv;
    }
    __syncthreads();
    int w = t >> 6, ln = t & 63, l16 = ln & 15, quad = ln >> 4;
    int orow = 16*w + l16;
    short8 wq[2], wk[2], wv[2];
    #pragma unroll
    for (int kf = 0; kf < 2; ++kf) {
        if (EMIT & 1) {
            const float* p = Wq + orow*64 + kf*32 + quad*8;
            #pragma unroll
            for (int j = 0; j < 8; ++j) wq[kf][j] = f2bf(p[j]);
        }
        if (EMIT & 2) {
            const float* p = Wk + orow*64 + kf*32 + quad*8;
            #pragma unroll
            for (int j = 0; j < 8; ++j) wk[kf][j] = f2bf(p[j]);
        }
        if (EMIT & 4) {
            const float* p = Wv + orow*64 + kf*32 + quad*8;
            #pragma unroll
            for (int j = 0; j < 8; ++j) wv[kf][j] = f2bf(p[j]);
        }
    }
    #pragma unroll
    for (int nt = 0; nt < 8; ++nt) {
        int px = nt*16 + l16;
        short8 xb0 = *(const short8*)(T + SWV(px, quad*8));
        short8 xb1 = *(const short8*)(T + SWV(px, 32 + quad*8));
        // head-major base: head = w, channels quad*4..+3 within head
        size_t hmbase = (((size_t)(b*4 + w))*NPX + row*NHW + px)*16 + quad*4;
        if (EMIT & 1) {
            f4 acc = {0.f,0.f,0.f,0.f};
            acc = MFMA(wq[0], xb0, acc); acc = MFMA(wq[1], xb1, acc);
            short4v sv;
            #pragma unroll
            for (int r = 0; r < 4; ++r) sv[r] = f2bf(acc[r] * QSCALE);
            *(short4v*)(Qp + hmbase) = sv;
        }
        if (EMIT & 2) {
            f4 acc = {0.f,0.f,0.f,0.f};
            acc = MFMA(wk[0], xb0, acc); acc = MFMA(wk[1], xb1, acc);
            short4v sv;
            #pragma unroll
            for (int r = 0; r < 4; ++r) sv[r] = f2bf(acc[r]);
            *(short4v*)(Kp + hmbase) = sv;
        }
        if (EMIT & 4) {
            f4 acc = {0.f,0.f,0.f,0.f};
            acc = MFMA(wv[0], xb0, acc); acc = MFMA(wv[1], xb1, acc);
            #pragma unroll
            for (int r = 0; r < 4; ++r)
                Vp[((size_t)(b*64 + 16*w + quad*4 + r))*NPX + row*NHW + px] = f2bf(acc[r]);
        }
    }
}

// single-source projection (fallback paths)
template<int EMIT>
__global__ __launch_bounds__(256, 6) void k_proj(
    const float* __restrict__ src, const float* __restrict__ gate,
    const float* __restrict__ Wq, const float* __restrict__ Wk, const float* __restrict__ Wv,
    short* __restrict__ Qp, short* __restrict__ Kp, short* __restrict__ Vp) {
    __shared__ __align__(16) short T[8192];
    proj_body<EMIT>(src, gate, Wq, Wk, Wv, Qp, Kp, Vp, T,
                    blockIdx.x >> 7, blockIdx.x & 127, threadIdx.x);
}

// fused both-source projection: bidx&7 = (srcsel<<2)|b region -> XCD-local
__global__ __launch_bounds__(256, 6) void k_proj2(
    const float* __restrict__ s0, const float* __restrict__ s1, const float* __restrict__ gate,
    const float* __restrict__ Wq0, const float* __restrict__ Wk0, const float* __restrict__ Wv0,
    const float* __restrict__ Wq1, const float* __restrict__ Wk1, const float* __restrict__ Wv1,
    short* __restrict__ Q0, short* __restrict__ K0, short* __restrict__ V0,
    short* __restrict__ Q1, short* __restrict__ K1, short* __restrict__ V1) {
    __shared__ __align__(16) short T[8192];
    int region = blockIdx.x & 7;
    int ss = region >> 2, b = region & 3, row = blockIdx.x >> 3;
    if (ss == 0)
        proj_body<7>(s0, nullptr, Wq0, Wk0, Wv0, Q0, K0, V0, T, b, row, threadIdx.x);
    else
        proj_body<7>(s1, gate, Wq1, Wk1, Wv1, Q1, K1, V1, T, b, row, threadIdx.x);
}

// ---------------- windowed cross attention (S, softmax, PV only) ----------------
// SWZ=1 (fused, grid=8*NL): blockIdx%8 -> (pass,b): each XCD owns one plane.
// Q/K head-major [(b*4+h)][px][16]: fragment loads 32 B-dense per pixel.
// S computed transposed (A=K, B=Q); P_hat unnormalized; softmax via exp2
// (Q pre-scaled by 0.25*log2e, exact); denom via MFMA ones-trick.
// scr: [pass][4 parity][nb][px][64] bf16; same-parity windows tile the plane.
template<int SWZ>
__global__ __launch_bounds__(256, 8) void k_attn(
    const short* __restrict__ Q0, const short* __restrict__ K0, const short* __restrict__ V0,
    const short* __restrict__ Q1, const short* __restrict__ K1, const short* __restrict__ V1,
    short* __restrict__ scr, size_t scr_stride, int nb) {
    __shared__ __align__(16) short Pb[4][1024];   // per-wave P^T-view [16 n][64 m], swizzled
    int bidx = blockIdx.x;
    int pass, b, l;
    if (SWZ) {
        int region = bidx & 7;
        pass = region >> 2; b = region & 3; l = bidx >> 3;
    } else {
        int per = nb * NL;
        pass = bidx / per; int rem2 = bidx - pass*per;
        b = rem2 / NL; l = rem2 - b*NL;
    }
    const short* Qp = pass ? Q1 : Q0;
    const short* Kp = pass ? K1 : K0;
    const short* Vp = pass ? V1 : V0;
    short* scrp = scr + (size_t)pass * scr_stride;
    int wr = l / NWIN, wc = l - (l/NWIN)*NWIN;
    int row0 = wr*4, col0 = wc*4;
    int parity = (wr & 1)*2 + (wc & 1);
    int t = threadIdx.x, w = t >> 6, ln = t & 63, l16 = ln & 15, quad = ln >> 4;
    int h = w;
    short* PT = Pb[w];
    short8 z = {0,0,0,0,0,0,0,0};
    const short one = (short)0x3F80;   // bf16 1.0
    short8 ones = {one,one,one,one,one,one,one,one};
    const short* Qh = Qp + ((size_t)(b*4 + h))*NPX*16;
    const short* Kh = Kp + ((size_t)(b*4 + h))*NPX*16;

    // K frags: lane l16 = m pixel, k = d = quad*8+j (quad<2); head-major 32 B/px
    short8 kb[4];
    #pragma unroll
    for (int mt = 0; mt < 4; ++mt) {
        int m = mt*16 + l16;
        int px = (row0 + (m >> 3))*NHW + col0 + (m & 7);
        kb[mt] = (quad < 2) ? *(const short8*)(Kh + (size_t)px*16 + quad*8) : z;
    }
    // V A-frags: A[row=d=l16][k=m]; planar V: row rr, 8 consecutive cols
    short8 va0, va1;
    {
        const short* vb = Vp + ((size_t)(b*64 + h*16 + l16))*NPX;
        const short* p0 = vb + (row0 + quad)*NHW + col0;
        const short* p1 = vb + (row0 + 4 + quad)*NHW + col0;
        short4v a = *(const short4v*)p0, bq = *(const short4v*)(p0 + 4);
        short4v c = *(const short4v*)p1, d = *(const short4v*)(p1 + 4);
        #pragma unroll
        for (int j = 0; j < 4; ++j) { va0[j] = a[j]; va0[4+j] = bq[j]; va1[j] = c[j]; va1[4+j] = d[j]; }
    }

    #pragma unroll
    for (int ntl = 0; ntl < 4; ++ntl) {
        int n = ntl*16 + l16;
        int px = (row0 + (n >> 3))*NHW + col0 + (n & 7);
        short8 qa = (quad < 2) ? *(const short8*)(Qh + (size_t)px*16 + quad*8) : z;
        // S^T tiles: D[i=m][j=n]; lane value r -> m = mt*16+quad*4+r, n = ntl*16+l16
        #pragma unroll
        for (int mt = 0; mt < 4; ++mt) {
            f4 zz = {0.f,0.f,0.f,0.f};
            f4 s = MFMA(kb[mt], qa, zz);
            short4v pv;
            #pragma unroll
            for (int r = 0; r < 4; ++r)
                pv[r] = f2bft(exp2f(fminf(s[r], 43.f)));
            *(short4v*)(PT + SWV(l16, mt*16 + quad*4)) = pv;   // 4 contiguous cols
        }
        // O[d][n] = V_h P^T; denom[n] = ones * P^T (same B-frags, col-aligned)
        short8 pb0 = *(const short8*)(PT + SWV(l16, quad*8));
        short8 pb1 = *(const short8*)(PT + SWV(l16, 32 + quad*8));
        f4 o = {0.f,0.f,0.f,0.f};
        o = MFMA(va0, pb0, o);
        o = MFMA(va1, pb1, o);
        f4 dn = {0.f,0.f,0.f,0.f};
        dn = MFMA(ones, pb0, dn);
        dn = MFMA(ones, pb1, dn);
        float inv = __builtin_amdgcn_rcpf(dn[0]);
        short4v sv;
        #pragma unroll
        for (int r = 0; r < 4; ++r) sv[r] = f2bf(o[r] * inv);
        *(short4v*)(scrp + (((size_t)(parity*nb + b))*NPX + px)*64 + h*16 + quad*4) = sv;
    }
}

// ---------------- fold + mask + 1x1 proj + residual, pure-MFMA, no LDS ----------------
template<int SWZ>
__global__ __launch_bounds__(256, 6) void k_gather(
    const short* __restrict__ scr, size_t scr_stride,
    const float* __restrict__ r0, const float* __restrict__ r1,
    const short* __restrict__ wpb,
    float* __restrict__ o0, float* __restrict__ o1, int nb) {
    int bidx = blockIdx.x;
    int pass, b, hh, half;
    if (SWZ) {
        int region = bidx & 7;
        pass = region >> 2; b = region & 3;
        int rem2 = bidx >> 3; hh = rem2 >> 1; half = rem2 & 1;
    } else {
        pass = 0;
        b = bidx / (NHW*2); int rem2 = bidx - b*(NHW*2);
        hh = rem2 >> 1; half = rem2 & 1;
    }
    const short* scrp = scr + (size_t)pass * scr_stride;
    const float* resid = pass ? r1 : r0;
    const short* wproj = wpb + (SWZ ? pass*4096 : 0);
    float* outp = pass ? o1 : o0;
    int t = threadIdx.x, w = t >> 6, ln = t & 63, l16 = ln & 15, quad = ln >> 4;
    int px = half*64 + w*16 + l16;          // this lane's pixel column
    int rlo, rhi, clo, chi;
    wrange(hh, rlo, rhi); wrange(px, clo, chi);
    bool okr0 = (rhi > rlo) || ((rlo & 1) == 0);
    bool okr1 = (rhi > rlo) || ((rlo & 1) == 1);
    bool okc0 = (chi > clo) || ((clo & 1) == 0);
    bool okc1 = (chi > clo) || ((clo & 1) == 1);
    short8 wa[4][2];
    #pragma unroll
    for (int ct = 0; ct < 4; ++ct)
        #pragma unroll
        for (int kf = 0; kf < 2; ++kf)
            wa[ct][kf] = *(const short8*)(wproj + (ct*16 + l16)*64 + kf*32 + quad*8);
    f4 acc[4];
    #pragma unroll
    for (int ct = 0; ct < 4; ++ct) acc[ct] = (f4){0.f,0.f,0.f,0.f};
    short8 z = {0,0,0,0,0,0,0,0};
    #pragma unroll
    for (int par = 0; par < 4; ++par) {
        bool valid = ((par >> 1) ? okr1 : okr0) && ((par & 1) ? okc1 : okc0);
        const short* sp2 = scrp + (((size_t)(par*nb + b))*NPX + hh*NHW + px)*64;
        short8 b0 = *(const short8*)(sp2 + quad*8);
        short8 b1 = *(const short8*)(sp2 + 32 + quad*8);
        if (!valid) { b0 = z; b1 = z; }
        #pragma unroll
        for (int ct = 0; ct < 4; ++ct) {
            acc[ct] = MFMA(wa[ct][0], b0, acc[ct]);
            acc[ct] = MFMA(wa[ct][1], b1, acc[ct]);
        }
    }
    float inv = 1.f / ((float)(rhi - rlo + 1) * (float)(chi - clo + 1));
    #pragma unroll
    for (int ct = 0; ct < 4; ++ct)
        #pragma unroll
        for (int r = 0; r < 4; ++r) {
            size_t gi = (((size_t)(b*64 + ct*16 + quad*4 + r))*NHW + hh)*NHW + px;
            outp[gi] = resid[gi] + acc[ct][r] * inv;
        }
}

extern "C" void kernel_launch(void* const* d_in, const int* in_sizes, int n_in,
                              void* d_out, int out_size, void* d_ws, size_t ws_size,
                              hipStream_t stream) {
    const float* low  = (const float*)d_in[0];
    const float* high = (const float*)d_in[1];
    const float* w_ql = (const float*)d_in[2];
    const float* w_kh = (const float*)d_in[3];
    const float* w_vh = (const float*)d_in[4];
    const float* w_qh = (const float*)d_in[5];
    const float* w_kl = (const float*)d_in[6];
    const float* w_vl = (const float*)d_in[7];
    const float* w_pl = (const float*)d_in[8];
    const float* w_ph = (const float*)d_in[9];
    float* out = (float*)d_out;
    float* pooled = (float*)d_ws;
    float* sgate  = pooled + 256;
    short* wbf = (short*)((char*)d_ws + 2048);          // 2 x 4096 bf16 Wp
    short* base = wbf + 8192;
    const size_t PL = (size_t)NB * NPX * 64;            // elems per bf16 plane (8.39 MB)
    const size_t plane_f = (size_t)NB * 64 * NPX;       // fp32 out plane elems
    const size_t SCR = 4 * PL;                          // scr elems per pass (33.5 MB)
    const size_t HDR = 2048 + 8192*sizeof(short);
    size_t need_fused  = HDR + (6*PL + 2*SCR) * sizeof(short);
    size_t need_serial = HDR + (6*PL + SCR) * sizeof(short);
    size_t scr_elems_per_b = 4 * (size_t)NPX * 64;

    k_pool<<<dim3(NB*64), dim3(256), 0, stream>>>(high, pooled);
    k_gate<<<dim3(1), dim3(256), 0, stream>>>(pooled,
        (const float*)d_in[10], (const float*)d_in[11],
        (const float*)d_in[12], (const float*)d_in[13],
        (const float*)d_in[14], (const float*)d_in[15],
        w_pl, w_ph, sgate, wbf);

    if (ws_size >= need_serial) {
        short* QL = base;        short* KL = base + PL;   short* VL = base + 2*PL;
        short* QH = base + 3*PL; short* KH = base + 4*PL; short* VH = base + 5*PL;
        short* scr = base + 6*PL;
        k_proj2<<<dim3(8*NHW), dim3(256), 0, stream>>>(low, high, sgate,
            w_ql, w_kl, w_vl, w_qh, w_kh, w_vh,
            QL, KL, VL, QH, KH, VH);
        if (ws_size >= need_fused) {
            k_attn<1><<<dim3(8*NL), dim3(256), 0, stream>>>(QL, KH, VH, QH, KL, VL, scr, SCR, NB);
            k_gather<1><<<dim3(8*NHW*2), dim3(256), 0, stream>>>(scr, SCR, low, high,
                wbf, out, out + plane_f, NB);
        } else {
            k_attn<0><<<dim3(NB*NL), dim3(256), 0, stream>>>(QL, KH, VH, nullptr, nullptr, nullptr, scr, 0, NB);
            k_gather<0><<<dim3(NB*NHW*2), dim3(256), 0, stream>>>(scr, 0, low, nullptr,
                wbf, out, nullptr, NB);
            k_attn<0><<<dim3(NB*NL), dim3(256), 0, stream>>>(QH, KL, VL, nullptr, nullptr, nullptr, scr, 0, NB);
            k_gather<0><<<dim3(NB*NHW*2), dim3(256), 0, stream>>>(scr, 0, high, nullptr,
                wbf + 4096, out + plane_f, nullptr, NB);
        }
    } else {
        // trio mode: 3 plane slots + batch-chunked scr
        short* P0 = base; short* P1 = base + PL; short* P2 = base + 2*PL;
        short* scr = base + 3*PL;
        int nbc = 0;
        for (int n = NB; n >= 1; n >>= 1)
            if (ws_size >= HDR + (3*PL + n*scr_elems_per_b)*sizeof(short)) { nbc = n; break; }
        if (nbc == 0) nbc = 1;
        for (int pass = 0; pass < 2; ++pass) {
            const float* qsrc = pass ? high : low;
            const float* ksrc = pass ? low  : high;
            const float* qg   = pass ? sgate : nullptr;
            const float* kg   = pass ? nullptr : sgate;
            const float* Wq   = pass ? w_qh : w_ql;
            const float* Wk   = pass ? w_kl : w_kh;
            const float* Wv   = pass ? w_vl : w_vh;
            const short* Wpb  = wbf + pass*4096;
            const float* resid = pass ? high : low;
            float* op = out + (size_t)pass * plane_f;
            k_proj<1><<<dim3(NB*NHW), dim3(256), 0, stream>>>(qsrc, qg, Wq, nullptr, nullptr, P0, nullptr, nullptr);
            k_proj<6><<<dim3(NB*NHW), dim3(256), 0, stream>>>(ksrc, kg, nullptr, Wk, Wv, nullptr, P1, P2);
            for (int b0 = 0; b0 < NB; b0 += nbc) {
                int nb = (NB - b0) < nbc ? (NB - b0) : nbc;
                size_t boff = (size_t)b0 * NPX * 64;
                k_attn<0><<<dim3(nb*NL), dim3(256), 0, stream>>>(P0 + boff, P1 + boff, P2 + boff,
                    nullptr, nullptr, nullptr, scr, 0, nb);
                k_gather<0><<<dim3(nb*NHW*2), dim3(256), 0, stream>>>(scr, 0, resid + boff, nullptr,
                    Wpb, op + boff, nullptr, nb);
            }
        }
    }
}